// Round 10
// baseline (1436.942 us; speedup 1.0000x reference)
//
#include <hip/hip_runtime.h>
#include <hip/hip_bf16.h>
#include <math.h>

#define NROWS 16384
#define HID 64
#define KSPLIT 8
#define KCH (NROWS / KSPLIT)   // 2048
#define STK 128                // stage depth in k-floats
#define NSTAGE (KCH / STK)     // 16

typedef __attribute__((ext_vector_type(8))) __bf16 bf16x8;
typedef __attribute__((ext_vector_type(4))) float f32x4;

__device__ inline f32x4 mfma16(bf16x8 a, bf16x8 b, f32x4 c) {
    return __builtin_amdgcn_mfma_f32_16x16x32_bf16(a, b, c, 0, 0, 0);
}

__device__ inline void split8v(const f32x4 v0, const f32x4 v1, bf16x8& h, bf16x8& l) {
    float f[8] = {v0[0], v0[1], v0[2], v0[3], v1[0], v1[1], v1[2], v1[3]};
#pragma unroll
    for (int j = 0; j < 8; ++j) {
        __bf16 hh = (__bf16)f[j];
        h[j] = hh;
        l[j] = (__bf16)(f[j] - (float)hh);
    }
}

// ---------------------------------------------------------------------------
// pack_b: x [16384,64] fp32 row-major  ->  MFMA B-fragment-ordered bf16 hi/lo.
// ---------------------------------------------------------------------------
__global__ __launch_bounds__(256) void pack_b(const float* __restrict__ x,
                                              __bf16* __restrict__ hi,
                                              __bf16* __restrict__ lo) {
    __shared__ float tile[32 * 64];
    const int kb = blockIdx.x;  // 0..511, 32 k-rows each
    const f32x4* src = (const f32x4*)(x + (size_t)kb * 32 * 64);
    f32x4* dst = (f32x4*)tile;
    dst[threadIdx.x] = src[threadIdx.x];
    dst[threadIdx.x + 256] = src[threadIdx.x + 256];
    __syncthreads();
    const int t = threadIdx.x >> 6;    // n-tile 0..3
    const int l = threadIdx.x & 63;    // consumer lane
    const int col = (t << 4) + (l & 15);
    const int krow = (l >> 4) * 8;
    bf16x8 h8, l8;
#pragma unroll
    for (int j = 0; j < 8; ++j) {
        float v = tile[(krow + j) * 64 + col];
        __bf16 hh = (__bf16)v;
        h8[j] = hh;
        l8[j] = (__bf16)(v - (float)hh);
    }
    const size_t base = (((size_t)kb * 4 + t) * 64 + l) * 8;
    *(bf16x8*)(hi + base) = h8;
    *(bf16x8*)(lo + base) = l8;
}

// ---------------------------------------------------------------------------
// gemm_partial: unchanged from r9 (equal-best 588 us). LDS-staged contiguous
// A-reads, swizzled ds_read, T14 async split, cross-wave K-reduction.
// ---------------------------------------------------------------------------
__global__ __launch_bounds__(256, 4) void gemm_partial(const float* __restrict__ adj,
                                                       const __bf16* __restrict__ Bhi,
                                                       const __bf16* __restrict__ Blo,
                                                       float* __restrict__ partial) {
    __shared__ char lds_raw[32768];  // 2 x 16KB stage buffers; reused as red

    const int tid = threadIdx.x;
    const int lane = tid & 63;
    const int wv = tid >> 6;          // wave 0..3 -> k-substep within stage
    const int rt = blockIdx.x & 511;  // row-tile (32 rows)
    const int ks = blockIdx.x >> 9;   // k-split 0..7
    const int rbase = rt * 32;
    const int rq = lane & 15;
    const int kq = lane >> 4;

    f32x4 acc[2][4];
#pragma unroll
    for (int g = 0; g < 2; ++g)
#pragma unroll
        for (int t = 0; t < 4; ++t) acc[g][t] = f32x4{0.f, 0.f, 0.f, 0.f};

    const int srow = tid >> 5;
    const int scol = tid & 31;
    const int sw = (srow & 7) << 4;
    const float* agbase = adj + (size_t)(rbase + srow) * NROWS + ks * KCH + scol * 4;

    f32x4 areg[4];
#pragma unroll
    for (int i = 0; i < 4; ++i)
        areg[i] = *(const f32x4*)(agbase + (size_t)i * 8 * NROWS);
#pragma unroll
    for (int i = 0; i < 4; ++i)
        *(f32x4*)(lds_raw + (srow + 8 * i) * 512 + ((scol * 16) ^ sw)) = areg[i];
    __syncthreads();

    for (int s = 0; s < NSTAGE; ++s) {
        const int buf = s & 1;
        if (s + 1 < NSTAGE) {
#pragma unroll
            for (int i = 0; i < 4; ++i)
                areg[i] = *(const f32x4*)(agbase + (size_t)i * 8 * NROWS +
                                          (s + 1) * STK);
        }
        {
            const size_t bb = (size_t)(ks * 64 + s * 4 + wv) * 2048 + (size_t)lane * 8;
            bf16x8 bh[4], bl[4];
#pragma unroll
            for (int t = 0; t < 4; ++t) {
                bh[t] = *(const bf16x8*)(Bhi + bb + (size_t)t * 512);
                bl[t] = *(const bf16x8*)(Blo + bb + (size_t)t * 512);
            }
            char* base = lds_raw + buf * 16384;
            const int kb = wv * 128 + kq * 32;
            const int rsw = (rq & 7) << 4;
            f32x4 a0lo = *(const f32x4*)(base + rq * 512 + (kb ^ rsw));
            f32x4 a0hi = *(const f32x4*)(base + rq * 512 + ((kb + 16) ^ rsw));
            f32x4 a1lo = *(const f32x4*)(base + (16 + rq) * 512 + (kb ^ rsw));
            f32x4 a1hi = *(const f32x4*)(base + (16 + rq) * 512 + ((kb + 16) ^ rsw));
            bf16x8 ah0, al0, ah1, al1;
            split8v(a0lo, a0hi, ah0, al0);
            split8v(a1lo, a1hi, ah1, al1);
#pragma unroll
            for (int t = 0; t < 4; ++t) {
                acc[0][t] = mfma16(ah0, bh[t], acc[0][t]);
                acc[0][t] = mfma16(ah0, bl[t], acc[0][t]);
                acc[0][t] = mfma16(al0, bh[t], acc[0][t]);
                acc[1][t] = mfma16(ah1, bh[t], acc[1][t]);
                acc[1][t] = mfma16(ah1, bl[t], acc[1][t]);
                acc[1][t] = mfma16(al1, bh[t], acc[1][t]);
            }
        }
        if (s + 1 < NSTAGE) {
#pragma unroll
            for (int i = 0; i < 4; ++i)
                *(f32x4*)(lds_raw + (buf ^ 1) * 16384 + (srow + 8 * i) * 512 +
                          ((scol * 16) ^ sw)) = areg[i];
        }
        __syncthreads();
    }

    // C/D layout: col = lane&15, row = (lane>>4)*4 + reg   [m89-verified]
    float(*red)[32][64] = (float(*)[32][64])lds_raw;
#pragma unroll
    for (int g = 0; g < 2; ++g)
#pragma unroll
        for (int t = 0; t < 4; ++t)
#pragma unroll
            for (int r = 0; r < 4; ++r)
                red[wv][g * 16 + kq * 4 + r][t * 16 + rq] = acc[g][t][r];
    __syncthreads();

    const int row = tid >> 3;
    const int c0 = (tid & 7) * 8;
    f32x4 s0 = f32x4{0.f, 0.f, 0.f, 0.f};
    f32x4 s1 = f32x4{0.f, 0.f, 0.f, 0.f};
#pragma unroll
    for (int w = 0; w < 4; ++w) {
        s0 += *(const f32x4*)&red[w][row][c0];
        s1 += *(const f32x4*)&red[w][row][c0 + 4];
    }
    float* pp = partial + (size_t)ks * (NROWS * HID) + (size_t)(rbase + row) * HID + c0;
    __builtin_nontemporal_store(s0, (f32x4*)pp);
    __builtin_nontemporal_store(s1, (f32x4*)(pp + 4));
}

// ---------------------------------------------------------------------------
// reduce_dense: agg_r = sum_ks partial[ks][r]; x_out[r] = tanh([agg_r|x_r] @ W)
// ---------------------------------------------------------------------------
__global__ __launch_bounds__(256) void reduce_dense(const float* __restrict__ partial,
                                                    const float* __restrict__ xin,
                                                    const float* __restrict__ W,
                                                    float* __restrict__ xout) {
    __shared__ float wsm[128 * 64];  // 32 KB
    const f32x4* wsrc = (const f32x4*)W;
    f32x4* wdst = (f32x4*)wsm;
#pragma unroll
    for (int i = 0; i < 8; ++i) wdst[threadIdx.x + 256 * i] = wsrc[threadIdx.x + 256 * i];
    __syncthreads();

    const int lane = threadIdx.x & 63;
    const int wv = threadIdx.x >> 6;
    const int r0 = blockIdx.x * 32 + wv * 8;
#pragma unroll 2
    for (int i = 0; i < 8; ++i) {
        const int r = r0 + i;
        float av = 0.f;
#pragma unroll
        for (int ks = 0; ks < KSPLIT; ++ks)
            av += partial[(size_t)ks * (NROWS * HID) + (size_t)r * HID + lane];
        const float xv = xin[(size_t)r * HID + lane];
        float z = 0.f;
#pragma unroll
        for (int j = 0; j < 64; ++j) z += __shfl(av, j) * wsm[j * 64 + lane];
#pragma unroll
        for (int j = 0; j < 64; ++j) z += __shfl(xv, j) * wsm[(64 + j) * 64 + lane];
        xout[(size_t)r * HID + lane] = tanhf(z);
    }
}

// ---------------------------------------------------------------------------
// read_probe (MEASUREMENT, this round only): pure-read bandwidth of adj with
// ideal streaming shape -- wave-contiguous 1KB runs, 32 waves/CU, 5 passes
// (5.35 GB). Sized to exceed the ~660us harness fills so its counter row
// (dur_us, hbm_gbps, FETCH_SIZE) lands in the top-5 table. Discriminates:
// H1 machine read-ceiling ~4.2 TB/s (probe ~1300us) vs H2 gemm-specific
// interference (probe ~830us at ~6.4 TB/s). Deterministic; sums to sink.
// ---------------------------------------------------------------------------
__global__ __launch_bounds__(256) void read_probe(const float* __restrict__ adj,
                                                  float* __restrict__ sink) {
    const size_t n4 = (size_t)NROWS * NROWS / 4;   // 67,108,864 f32x4
    const size_t stride = (size_t)gridDim.x * blockDim.x;
    const size_t gid = (size_t)blockIdx.x * blockDim.x + threadIdx.x;
    const f32x4* src = (const f32x4*)adj;
    f32x4 acc = f32x4{0.f, 0.f, 0.f, 0.f};
#pragma unroll 1
    for (int p = 0; p < 5; ++p) {
#pragma unroll 1
        for (size_t i = gid; i < n4; i += stride) acc += src[i];
    }
    sink[gid] = acc[0] + acc[1] + acc[2] + acc[3];
}

extern "C" void kernel_launch(void* const* d_in, const int* in_sizes, int n_in,
                              void* d_out, int out_size, void* d_ws, size_t ws_size,
                              hipStream_t stream) {
    const float* x0 = (const float*)d_in[0];   // user_embs [16384,64]
    const float* adj = (const float*)d_in[1];  // adj [16384,16384]
    const float* W = (const float*)d_in[2];    // W [2,128,64]
    float* out = (float*)d_out;

    char* ws = (char*)d_ws;
    __bf16* Bhi = (__bf16*)(ws);                       // 2 MB
    __bf16* Blo = (__bf16*)(ws + (2u << 20));          // 2 MB
    float* partial = (float*)(ws + (4u << 20));        // 32 MB (8 x 4 MB)
    float* x1 = (float*)(ws + (36u << 20));            // 4 MB
    float* sink = (float*)(ws + (40u << 20));          // 2 MB probe sink

    // hop 0
    pack_b<<<512, 256, 0, stream>>>(x0, Bhi, Blo);
    gemm_partial<<<KSPLIT * 512, 256, 0, stream>>>(adj, Bhi, Blo, partial);
    reduce_dense<<<512, 256, 0, stream>>>(partial, x0, W, x1);
    // hop 1
    pack_b<<<512, 256, 0, stream>>>(x1, Bhi, Blo);
    gemm_partial<<<KSPLIT * 512, 256, 0, stream>>>(adj, Bhi, Blo, partial);
    reduce_dense<<<512, 256, 0, stream>>>(partial, x1, W + 128 * 64, out);
    // measurement probe (appended last; remove next round)
    read_probe<<<2048, 256, 0, stream>>>(adj, sink);
}

// Round 11
// 722.800 us; speedup vs baseline: 1.9880x; 1.9880x over previous
//
#include <hip/hip_runtime.h>
#include <hip/hip_bf16.h>
#include <math.h>

#define NROWS 16384
#define HID 64
#define KSPLIT 8
#define KCH (NROWS / KSPLIT)  // 2048
#define NSTEP (KCH / 32)      // 64

typedef __attribute__((ext_vector_type(8))) __bf16 bf16x8;
typedef __attribute__((ext_vector_type(4))) float f32x4;

__device__ inline f32x4 mfma16(bf16x8 a, bf16x8 b, f32x4 c) {
    return __builtin_amdgcn_mfma_f32_16x16x32_bf16(a, b, c, 0, 0, 0);
}

__device__ inline void split8v(const f32x4 v0, const f32x4 v1, bf16x8& h, bf16x8& l) {
    float f[8] = {v0[0], v0[1], v0[2], v0[3], v1[0], v1[1], v1[2], v1[3]};
#pragma unroll
    for (int j = 0; j < 8; ++j) {
        __bf16 hh = (__bf16)f[j];
        h[j] = hh;
        l[j] = (__bf16)(f[j] - (float)hh);
    }
}

// ---------------------------------------------------------------------------
// pack_b: x [16384,64] fp32 row-major  ->  MFMA B-fragment-ordered bf16 hi/lo.
// ---------------------------------------------------------------------------
__global__ __launch_bounds__(256) void pack_b(const float* __restrict__ x,
                                              __bf16* __restrict__ hi,
                                              __bf16* __restrict__ lo) {
    __shared__ float tile[32 * 64];
    const int kb = blockIdx.x;  // 0..511, 32 k-rows each
    const f32x4* src = (const f32x4*)(x + (size_t)kb * 32 * 64);
    f32x4* dst = (f32x4*)tile;
    dst[threadIdx.x] = src[threadIdx.x];
    dst[threadIdx.x + 256] = src[threadIdx.x + 256];
    __syncthreads();
    const int t = threadIdx.x >> 6;    // n-tile 0..3
    const int l = threadIdx.x & 63;    // consumer lane
    const int col = (t << 4) + (l & 15);
    const int krow = (l >> 4) * 8;
    bf16x8 h8, l8;
#pragma unroll
    for (int j = 0; j < 8; ++j) {
        float v = tile[(krow + j) * 64 + col];
        __bf16 hh = (__bf16)v;
        h8[j] = hh;
        l8[j] = (__bf16)(v - (float)hh);
    }
    const size_t base = (((size_t)kb * 4 + t) * 64 + l) * 8;
    *(bf16x8*)(hi + base) = h8;
    *(bf16x8*)(lo + base) = l8;
}

// ---------------------------------------------------------------------------
// gemm_partial: partial[ks] = adj[:, ks-chunk] @ x[ks-chunk, :]
// SOFTWARE-PIPELINED register double-buffer (the r10 probe proved reads
// sustain 6.2 TB/s; every prior variant serialized [issue -> wait-ALL ->
// compute] per k-step because the consumed loads were the oldest in the
// vmcnt queue). Ping-pong Stage sets: issue stage s+1 BEFORE consuming
// stage s, so the consume's s_waitcnt drains only the older set while the
// younger 10 loads stay in flight across the boundary (counted-vmcnt, T4).
// 16-row waves (12 MFMA / 10 loads per step) so 2 sets + acc fit <=128
// VGPR -> __launch_bounds__(256,4): 4 waves/SIMD, 4 blocks/CU.
// Grid rt-major: co-resident blocks form a compact sweeping row window.
// adj loads plain (L1 merges half-line pairs; nt double-fetched, r3/r4).
// Partial stores nt (no reuse, keep L2 for B).
// ---------------------------------------------------------------------------
struct Stage {
    f32x4 a0, a1;
    bf16x8 bh0, bh1, bh2, bh3;
    bf16x8 bl0, bl1, bl2, bl3;
};

__device__ inline void stage_load(Stage& st, const float* __restrict__ ap,
                                  const __bf16* __restrict__ Bhi,
                                  const __bf16* __restrict__ Blo,
                                  int bbase, int sidx, int lane) {
    const f32x4* app = (const f32x4*)(ap + sidx * 32);
    st.a0 = app[0];                   // HBM stream: issue first
    st.a1 = app[1];
    const size_t bb = (size_t)(bbase + sidx) * 2048 + (size_t)lane * 8;
    st.bh0 = *(const bf16x8*)(Bhi + bb);
    st.bh1 = *(const bf16x8*)(Bhi + bb + 512);
    st.bh2 = *(const bf16x8*)(Bhi + bb + 1024);
    st.bh3 = *(const bf16x8*)(Bhi + bb + 1536);
    st.bl0 = *(const bf16x8*)(Blo + bb);
    st.bl1 = *(const bf16x8*)(Blo + bb + 512);
    st.bl2 = *(const bf16x8*)(Blo + bb + 1024);
    st.bl3 = *(const bf16x8*)(Blo + bb + 1536);
}

__device__ inline void stage_consume(const Stage& st, f32x4 acc[4]) {
    bf16x8 ah, al;
    split8v(st.a0, st.a1, ah, al);
    acc[0] = mfma16(ah, st.bh0, acc[0]);
    acc[0] = mfma16(ah, st.bl0, acc[0]);
    acc[0] = mfma16(al, st.bh0, acc[0]);
    acc[1] = mfma16(ah, st.bh1, acc[1]);
    acc[1] = mfma16(ah, st.bl1, acc[1]);
    acc[1] = mfma16(al, st.bh1, acc[1]);
    acc[2] = mfma16(ah, st.bh2, acc[2]);
    acc[2] = mfma16(ah, st.bl2, acc[2]);
    acc[2] = mfma16(al, st.bh2, acc[2]);
    acc[3] = mfma16(ah, st.bh3, acc[3]);
    acc[3] = mfma16(ah, st.bl3, acc[3]);
    acc[3] = mfma16(al, st.bh3, acc[3]);
}

__global__ __launch_bounds__(256, 4) void gemm_partial(const float* __restrict__ adj,
                                                       const __bf16* __restrict__ Bhi,
                                                       const __bf16* __restrict__ Blo,
                                                       float* __restrict__ partial) {
    const int lane = threadIdx.x & 63;
    const int wv = threadIdx.x >> 6;   // wave -> 16-row group
    const int rt = blockIdx.x >> 3;    // row-tile 0..255 (64 rows), rt-major
    const int ks = blockIdx.x & 7;     // k-split 0..7
    const int rbase = rt * 64 + wv * 16;
    const int rq = lane & 15;          // A row within group
    const int kq = lane >> 4;          // k-quarter 0..3

    f32x4 acc[4];
#pragma unroll
    for (int t = 0; t < 4; ++t) acc[t] = f32x4{0.f, 0.f, 0.f, 0.f};

    const float* ap = adj + (size_t)(rbase + rq) * NROWS + ks * KCH + kq * 8;
    const int bbase = ks * NSTEP;

    Stage sA, sB;
    stage_load(sA, ap, Bhi, Blo, bbase, 0, lane);
#pragma unroll 1
    for (int s = 0; s < NSTEP; s += 2) {
        stage_load(sB, ap, Bhi, Blo, bbase, s + 1, lane);   // younger set
        stage_consume(sA, acc);                             // waits only on sA
        if (s + 2 < NSTEP)
            stage_load(sA, ap, Bhi, Blo, bbase, s + 2, lane);
        stage_consume(sB, acc);
    }

    // C/D layout: col = lane&15, row = (lane>>4)*4 + reg   [m89-verified]
    float* pp = partial + (size_t)ks * (NROWS * HID) + (size_t)rbase * HID;
#pragma unroll
    for (int t = 0; t < 4; ++t)
#pragma unroll
        for (int r = 0; r < 4; ++r)
            __builtin_nontemporal_store(acc[t][r],
                pp + (kq * 4 + r) * HID + t * 16 + rq);
}

// ---------------------------------------------------------------------------
// reduce_dense: agg_r = sum_ks partial[ks][r]; x_out[r] = tanh([agg_r|x_r] @ W)
// ---------------------------------------------------------------------------
__global__ __launch_bounds__(256) void reduce_dense(const float* __restrict__ partial,
                                                    const float* __restrict__ xin,
                                                    const float* __restrict__ W,
                                                    float* __restrict__ xout) {
    __shared__ float wsm[128 * 64];  // 32 KB
    const f32x4* wsrc = (const f32x4*)W;
    f32x4* wdst = (f32x4*)wsm;
#pragma unroll
    for (int i = 0; i < 8; ++i) wdst[threadIdx.x + 256 * i] = wsrc[threadIdx.x + 256 * i];
    __syncthreads();

    const int lane = threadIdx.x & 63;
    const int wv = threadIdx.x >> 6;
    const int r0 = blockIdx.x * 32 + wv * 8;
#pragma unroll 2
    for (int i = 0; i < 8; ++i) {
        const int r = r0 + i;
        float av = 0.f;
#pragma unroll
        for (int ks = 0; ks < KSPLIT; ++ks)
            av += partial[(size_t)ks * (NROWS * HID) + (size_t)r * HID + lane];
        const float xv = xin[(size_t)r * HID + lane];
        float z = 0.f;
#pragma unroll
        for (int j = 0; j < 64; ++j) z += __shfl(av, j) * wsm[j * 64 + lane];
#pragma unroll
        for (int j = 0; j < 64; ++j) z += __shfl(xv, j) * wsm[(64 + j) * 64 + lane];
        xout[(size_t)r * HID + lane] = tanhf(z);
    }
}

extern "C" void kernel_launch(void* const* d_in, const int* in_sizes, int n_in,
                              void* d_out, int out_size, void* d_ws, size_t ws_size,
                              hipStream_t stream) {
    const float* x0 = (const float*)d_in[0];   // user_embs [16384,64]
    const float* adj = (const float*)d_in[1];  // adj [16384,16384]
    const float* W = (const float*)d_in[2];    // W [2,128,64]
    float* out = (float*)d_out;

    char* ws = (char*)d_ws;
    __bf16* Bhi = (__bf16*)(ws);                       // 2 MB
    __bf16* Blo = (__bf16*)(ws + (2u << 20));          // 2 MB
    float* partial = (float*)(ws + (4u << 20));        // 32 MB (8 x 4 MB)
    float* x1 = (float*)(ws + (36u << 20));            // 4 MB

    // hop 0
    pack_b<<<512, 256, 0, stream>>>(x0, Bhi, Blo);
    gemm_partial<<<KSPLIT * 256, 256, 0, stream>>>(adj, Bhi, Blo, partial);
    reduce_dense<<<512, 256, 0, stream>>>(partial, x0, W, x1);
    // hop 1
    pack_b<<<512, 256, 0, stream>>>(x1, Bhi, Blo);
    gemm_partial<<<KSPLIT * 256, 256, 0, stream>>>(adj, Bhi, Blo, partial);
    reduce_dense<<<512, 256, 0, stream>>>(partial, x1, W + 128 * 64, out);
}